// Round 7
// baseline (377.174 us; speedup 1.0000x reference)
//
#include <hip/hip_runtime.h>
#include <math.h>

#define B_ 2
#define T_ 2048
#define D_ 1024
#define H_ 16
#define HD_ 64
#define MAXLEN_ 2048
#define N3D_ 3072
#define M_ (B_ * T_)   // 4096
#define KA 1024        // GEMM K (plain bf16)

#define SCALE_L2E 0.18033688011116215f   // 0.125 * log2(e)
#define L2E 1.4426950408889634f

typedef unsigned short ushort_t;
typedef __attribute__((ext_vector_type(8))) short short8;
typedef __attribute__((ext_vector_type(4))) float floatx4;
typedef __attribute__((ext_vector_type(16))) float floatx16;
#define MFMA16(a, b, c) __builtin_amdgcn_mfma_f32_16x16x32_bf16(a, b, c, 0, 0, 0)
#define MFMA32(a, b, c) __builtin_amdgcn_mfma_f32_32x32x16_bf16(a, b, c, 0, 0, 0)

static __device__ __forceinline__ ushort_t f2bf(float f) {
    unsigned u = __float_as_uint(f);
    unsigned r = (u + 0x7FFFu + ((u >> 16) & 1u)) >> 16;
    return (ushort_t)r;
}
// pack two floats to packed bf16 pair (RNE), {lo=a, hi=b}
static __device__ __forceinline__ unsigned pack2bf(float a, float b) {
    unsigned ua = __float_as_uint(a), ub = __float_as_uint(b);
    ua = ua + 0x7FFFu + ((ua >> 16) & 1u);
    ub = ub + 0x7FFFu + ((ub >> 16) & 1u);
    return (ua >> 16) | (ub & 0xFFFF0000u);
}
// RTZ pack via v_perm: {lo=a_hi16, hi=b_hi16}
static __device__ __forceinline__ unsigned packrtz(float a, float b) {
    return __builtin_amdgcn_perm(__float_as_uint(b), __float_as_uint(a), 0x07060302u);
}

// async global->LDS, 16B per lane; lds dst = wave-uniform base + lane*16
static __device__ __forceinline__ void gld16(const ushort_t* g, ushort_t* l) {
    __builtin_amdgcn_global_load_lds(
        (const __attribute__((address_space(1))) void*)g,
        (__attribute__((address_space(3))) void*)l, 16, 0, 0);
}

// ---------------------------------------------------------------------------
// fp32 [rows][1024] -> bf16 [rows][1024], x | qkv_w | out_w in one launch
// ---------------------------------------------------------------------------
__global__ __launch_bounds__(256) void cvt_all(
    const float* __restrict__ x, const float* __restrict__ qw,
    const float* __restrict__ ow,
    ushort_t* __restrict__ Xc, ushort_t* __restrict__ QWc,
    ushort_t* __restrict__ OWc)
{
    const int row = blockIdx.x;
    const float* src; ushort_t* dst; int r;
    if (row < M_)            { src = x;  dst = Xc;  r = row; }
    else if (row < M_ + N3D_){ src = qw; dst = QWc; r = row - M_; }
    else                     { src = ow; dst = OWc; r = row - M_ - N3D_; }
    const int c = threadIdx.x * 4;
    float4 v = *(const float4*)(src + (size_t)r * 1024 + c);
    ushort4 hv;
    hv.x = f2bf(v.x); hv.y = f2bf(v.y); hv.z = f2bf(v.z); hv.w = f2bf(v.w);
    *(ushort4*)(dst + (size_t)r * KA + c) = hv;
}

// ---------------------------------------------------------------------------
// qkv MFMA GEMM. M=4096, N=3072, K=1024 bf16. 128x128 tile, 4 waves.
// Epilogue: Q -> Qs (pre-scaled by 0.125*log2e), K -> Khi, V -> Vt [B,H,HD,T].
// ---------------------------------------------------------------------------
__global__ __launch_bounds__(256) void qkv_mfma(
    const ushort_t* __restrict__ Ac, const ushort_t* __restrict__ Bc,
    const float* __restrict__ bias,
    ushort_t* __restrict__ Qs, ushort_t* __restrict__ Khi,
    ushort_t* __restrict__ Vt)
{
    __shared__ __align__(16) ushort_t As[16 * 512];
    __shared__ __align__(16) ushort_t Bs[16 * 512];
    const int tid = threadIdx.x;
    const int wv = tid >> 6, lane = tid & 63;
    const int l16 = lane & 15, quad = lane >> 4;
    const int wm = wv & 1, wn = wv >> 1;
    const int m0 = blockIdx.y * 128, n0 = blockIdx.x * 128;

    floatx4 acc[4][4];
#pragma unroll
    for (int i = 0; i < 4; ++i)
#pragma unroll
        for (int j = 0; j < 4; ++j) acc[i][j] = (floatx4){0.f, 0.f, 0.f, 0.f};

    for (int k0 = 0; k0 < KA; k0 += 64) {
        __syncthreads();
#pragma unroll
        for (int c = 0; c < 4; ++c) {
            const int b = wv * 4 + c;
            const int i = b >> 1, ks = b & 1;
            const int k = k0 + ks * 32 + quad * 8;
            gld16(Ac + (size_t)(m0 + i * 16 + l16) * KA + k, As + b * 512);
            gld16(Bc + (size_t)(n0 + i * 16 + l16) * KA + k, Bs + b * 512);
        }
        __syncthreads();
#pragma unroll
        for (int ks = 0; ks < 2; ++ks) {
            short8 af[4], bf[4];
#pragma unroll
            for (int ii = 0; ii < 4; ++ii)
                af[ii] = *(const short8*)(As + ((wm * 4 + ii) * 2 + ks) * 512 + lane * 8);
#pragma unroll
            for (int jj = 0; jj < 4; ++jj)
                bf[jj] = *(const short8*)(Bs + ((wn * 4 + jj) * 2 + ks) * 512 + lane * 8);
#pragma unroll
            for (int ii = 0; ii < 4; ++ii)
#pragma unroll
                for (int jj = 0; jj < 4; ++jj)
                    acc[ii][jj] = MFMA16(af[ii], bf[jj], acc[ii][jj]);
        }
    }

#pragma unroll
    for (int ii = 0; ii < 4; ++ii) {
#pragma unroll
        for (int r = 0; r < 4; ++r) {
            const int m = m0 + wm * 64 + ii * 16 + quad * 4 + r;
            const int bb = m >> 11, t = m & 2047;
#pragma unroll
            for (int jj = 0; jj < 4; ++jj) {
                const int n = n0 + wn * 64 + jj * 16 + l16;
                const int c = n >> 10, h = (n >> 6) & 15, hd = n & 63;
                const float v = acc[ii][jj][r] + bias[n];
                const size_t idx = (((size_t)bb * H_ + h) * T_ + t) * HD_ + hd;
                if (c == 0) { Qs[idx] = f2bf(v * SCALE_L2E); }
                else if (c == 1) { Khi[idx] = f2bf(v); }
                else { Vt[(((size_t)bb * H_ + h) * HD_ + hd) * T_ + t] = f2bf(v); }
            }
        }
    }
}

// ---------------------------------------------------------------------------
// out MFMA GEMM. M=4096, N=1024, K=1024. 128x64 tile (grid 512 = 2/CU).
// ---------------------------------------------------------------------------
__global__ __launch_bounds__(256) void out_mfma(
    const ushort_t* __restrict__ Ac, const ushort_t* __restrict__ Bc,
    const float* __restrict__ bias, float* __restrict__ Out)
{
    __shared__ __align__(16) ushort_t As[16 * 512];
    __shared__ __align__(16) ushort_t Bs[8 * 512];
    const int tid = threadIdx.x;
    const int wv = tid >> 6, lane = tid & 63;
    const int l16 = lane & 15, quad = lane >> 4;
    const int wm = wv & 1, wn = wv >> 1;
    const int m0 = blockIdx.y * 128, n0 = blockIdx.x * 64;

    floatx4 acc[4][2];
#pragma unroll
    for (int i = 0; i < 4; ++i)
#pragma unroll
        for (int j = 0; j < 2; ++j) acc[i][j] = (floatx4){0.f, 0.f, 0.f, 0.f};

    for (int k0 = 0; k0 < KA; k0 += 64) {
        __syncthreads();
#pragma unroll
        for (int c = 0; c < 4; ++c) {
            const int b = wv * 4 + c;
            const int i = b >> 1, ks = b & 1;
            const int k = k0 + ks * 32 + quad * 8;
            gld16(Ac + (size_t)(m0 + i * 16 + l16) * KA + k, As + b * 512);
        }
#pragma unroll
        for (int c = 0; c < 2; ++c) {
            const int b = wv * 2 + c;
            const int j = b >> 1, ks = b & 1;
            const int k = k0 + ks * 32 + quad * 8;
            gld16(Bc + (size_t)(n0 + j * 16 + l16) * KA + k, Bs + b * 512);
        }
        __syncthreads();
#pragma unroll
        for (int ks = 0; ks < 2; ++ks) {
            short8 af[4], bf[2];
#pragma unroll
            for (int ii = 0; ii < 4; ++ii)
                af[ii] = *(const short8*)(As + ((wm * 4 + ii) * 2 + ks) * 512 + lane * 8);
#pragma unroll
            for (int jj = 0; jj < 2; ++jj)
                bf[jj] = *(const short8*)(Bs + ((wn * 2 + jj) * 2 + ks) * 512 + lane * 8);
#pragma unroll
            for (int ii = 0; ii < 4; ++ii)
#pragma unroll
                for (int jj = 0; jj < 2; ++jj)
                    acc[ii][jj] = MFMA16(af[ii], bf[jj], acc[ii][jj]);
        }
    }

#pragma unroll
    for (int ii = 0; ii < 4; ++ii) {
#pragma unroll
        for (int r = 0; r < 4; ++r) {
            const int m = m0 + wm * 64 + ii * 16 + quad * 4 + r;
#pragma unroll
            for (int jj = 0; jj < 2; ++jj) {
                const int n = n0 + wn * 32 + jj * 16 + l16;
                Out[(size_t)m * D_ + n] = acc[ii][jj][r] + bias[n];
            }
        }
    }
}

// ---------------------------------------------------------------------------
// biasp[i] = dot(rel_pos[i,:], rpe_w) * log2(e)
// ---------------------------------------------------------------------------
__global__ __launch_bounds__(64) void rpe_project(
    const float* __restrict__ rel_pos, const float* __restrict__ rpe_w,
    float* __restrict__ biasp)
{
    const int i = blockIdx.x;
    const int lane = threadIdx.x;
    float v = rel_pos[(size_t)i * HD_ + lane] * rpe_w[lane];
#pragma unroll
    for (int off = 32; off; off >>= 1) v += __shfl_down(v, off);
    if (lane == 0) biasp[i] = v * L2E;
}

// ---------------------------------------------------------------------------
// Flash attention v3: 32x32x16 MFMA quadrants, K/V frags direct from global
// (register prefetch, no staging LDS), P-only LDS roundtrip (XOR-swizzled,
// double-buffered, one barrier per tile). No-max softmax (scores bounded),
// XCD-swizzled grid.
// Wave w of 4: S^T quadrant (k-block rw=w&1, q-block cw=w>>1);
//              O^T quadrant (hd-block rw,   q-block cw).
// ---------------------------------------------------------------------------
__global__ __launch_bounds__(256) void attn_mfma(
    const ushort_t* __restrict__ Qs, const ushort_t* __restrict__ Khi,
    const ushort_t* __restrict__ Vt, const float* __restrict__ biasp,
    ushort_t* __restrict__ AOc)
{
    __shared__ __align__(16) ushort_t PS[2][4096];  // P [64q][64k] swizzled
    __shared__ float LS[2][64];

    const int i = blockIdx.x;
    const int bh = (i & 7) + 8 * (i >> 8);
    const int q0 = ((i >> 3) & 31) * 64;
    const int tid = threadIdx.x;
    const int wv = tid >> 6, lane = tid & 63;
    const int l32 = lane & 31, half = lane >> 5;
    const int rw = wv & 1, cw = wv >> 1;

    const int qcol = q0 + cw * 32 + l32;
    const int qx = l32 & 7;                    // P swizzle key

    // Q B-fragments (persistent): B[n=l32][k=8*half+j], k-chunks of 16 per MFMA
    const ushort_t* gQ = Qs + ((size_t)bh * T_ + qcol) * HD_ + half * 8;
    short8 qf[4];
#pragma unroll
    for (int m = 0; m < 4; ++m) qf[m] = *(const short8*)(gQ + 16 * m);

    // K/V A-fragment base pointers (advance by k0 per tile)
    const ushort_t* gK = Khi + ((size_t)bh * T_ + rw * 32 + l32) * HD_ + half * 8;
    const ushort_t* gV = Vt  + ((size_t)bh * HD_ + rw * 32 + l32) * T_ + half * 8;

    short8 kf[4], vf[4];
#pragma unroll
    for (int m = 0; m < 4; ++m) {
        kf[m] = *(const short8*)(gK + 16 * m);
        vf[m] = *(const short8*)(gV + 16 * m);
    }

    floatx16 o_acc;
#pragma unroll
    for (int r = 0; r < 16; ++r) o_acc[r] = 0.f;
    float l_part = 0.f;

    const int ibias = 2047 + rw * 32 + half * 4 - qcol;

    for (int t = 0; t < 32; ++t) {
        const int k0 = t * 64;
        // ---- S^T quadrant: rows k = k0+32rw+..., cols q ----
        floatx16 s;
#pragma unroll
        for (int r = 0; r < 16; ++r) s[r] = 0.f;
#pragma unroll
        for (int m = 0; m < 4; ++m) s = MFMA32(kf[m], qf[m], s);
        // prefetch next K tile into same regs (reads past K stay inside ws)
#pragma unroll
        for (int m = 0; m < 4; ++m)
            kf[m] = *(const short8*)(gK + (size_t)(k0 + 64) * HD_ + 16 * m);

        // ---- p = exp2(s + bias); pack RTZ; write P quadrant (swizzled) ----
        ushort_t* pw = PS[t & 1] + (size_t)(cw * 32 + l32) * 64;
#pragma unroll
        for (int c = 0; c < 4; ++c) {
            float4 bb;
            __builtin_memcpy(&bb, biasp + (ibias + k0 + 8 * c), 16);
            float p0 = __builtin_amdgcn_exp2f(s[4 * c + 0] + bb.x);
            float p1 = __builtin_amdgcn_exp2f(s[4 * c + 1] + bb.y);
            float p2 = __builtin_amdgcn_exp2f(s[4 * c + 2] + bb.z);
            float p3 = __builtin_amdgcn_exp2f(s[4 * c + 3] + bb.w);
            l_part += (p0 + p1) + (p2 + p3);
            uint2 pk;
            pk.x = packrtz(p0, p1);
            pk.y = packrtz(p2, p3);
            *(uint2*)(pw + (((c + 4 * rw) ^ qx) * 8 + half * 4)) = pk;
        }
        __syncthreads();

        // ---- O^T += V^T P^T : A=V^T frag, B=P frag from LDS ----
        const ushort_t* pr = PS[t & 1] + (size_t)(cw * 32 + l32) * 64;
#pragma unroll
        for (int m = 0; m < 4; ++m) {
            const short8 pf = *(const short8*)(pr + ((2 * m + half) ^ qx) * 8);
            o_acc = MFMA32(vf[m], pf, o_acc);
        }
        // prefetch next V tile
#pragma unroll
        for (int m = 0; m < 4; ++m)
            vf[m] = *(const short8*)(gV + (k0 + 64) + 16 * m);
    }

    // ---- l reduction: in-lane partials -> cross-half -> cross-wave-pair ----
    l_part += __shfl_xor(l_part, 32);
    if (half == 0) LS[rw][cw * 32 + l32] = l_part;
    __syncthreads();
    const float inv = 1.0f / (LS[0][cw * 32 + l32] + LS[1][cw * 32 + l32]);

    // ---- epilogue: AOc[m=q][h*64+hd] bf16 (RNE) ----
    const int bb2 = bh >> 4, h2 = bh & 15;
    const size_t mrow = (size_t)bb2 * T_ + qcol;
#pragma unroll
    for (int c = 0; c < 4; ++c) {
        const int hd = rw * 32 + c * 8 + half * 4;
        uint2 pk;
        pk.x = pack2bf(o_acc[4 * c + 0] * inv, o_acc[4 * c + 1] * inv);
        pk.y = pack2bf(o_acc[4 * c + 2] * inv, o_acc[4 * c + 3] * inv);
        *(uint2*)(AOc + mrow * KA + h2 * 64 + hd) = pk;
    }
}

// ---------------------------------------------------------------------------
extern "C" void kernel_launch(void* const* d_in, const int* in_sizes, int n_in,
                              void* d_out, int out_size, void* d_ws, size_t ws_size,
                              hipStream_t stream)
{
    const float* x       = (const float*)d_in[0];
    const float* qkv_w   = (const float*)d_in[1];
    const float* qkv_b   = (const float*)d_in[2];
    const float* out_w   = (const float*)d_in[3];
    const float* out_b   = (const float*)d_in[4];
    const float* rel_pos = (const float*)d_in[5];
    const float* rpe_w   = (const float*)d_in[6];
    float* out = (float*)d_out;

    const size_t QE = (size_t)B_ * H_ * T_ * HD_;  // 4,194,304
    ushort_t* Qs  = (ushort_t*)d_ws;
    ushort_t* Khi = Qs  + QE;
    ushort_t* Vt  = Khi + QE;
    ushort_t* Xc  = Vt  + QE;                  // [4096][1024]
    ushort_t* QWc = Xc  + (size_t)M_ * KA;     // [3072][1024]
    ushort_t* OWc = QWc + (size_t)N3D_ * KA;   // [1024][1024]
    ushort_t* AOc = OWc + (size_t)D_ * KA;     // [4096][1024]
    float* biasp  = (float*)(AOc + (size_t)M_ * KA);

    cvt_all<<<M_ + N3D_ + D_, 256, 0, stream>>>(x, qkv_w, out_w, Xc, QWc, OWc);
    rpe_project<<<2 * MAXLEN_ - 1, 64, 0, stream>>>(rel_pos, rpe_w, biasp);

    qkv_mfma<<<dim3(N3D_ / 128, M_ / 128), 256, 0, stream>>>(
        Xc, QWc, qkv_b, Qs, Khi, Vt);
    attn_mfma<<<1024, 256, 0, stream>>>(Qs, Khi, Vt, biasp, AOc);
    out_mfma<<<dim3(D_ / 64, M_ / 128), 256, 0, stream>>>(
        AOc, OWc, out_b, out);
}

// Round 8
// 296.162 us; speedup vs baseline: 1.2735x; 1.2735x over previous
//
#include <hip/hip_runtime.h>
#include <math.h>

#define B_ 2
#define T_ 2048
#define D_ 1024
#define H_ 16
#define HD_ 64
#define MAXLEN_ 2048
#define N3D_ 3072
#define M_ (B_ * T_)   // 4096
#define KA 1024        // GEMM K (plain bf16)
#define QE_ 4194304    // B*H*T*HD

#define SCALE_L2E 0.18033688011116215f   // 0.125 * log2(e)
#define L2E 1.4426950408889634f

typedef unsigned short ushort_t;
typedef __attribute__((ext_vector_type(8))) short short8;
typedef __attribute__((ext_vector_type(4))) float floatx4;
#define MFMA16(a, b, c) __builtin_amdgcn_mfma_f32_16x16x32_bf16(a, b, c, 0, 0, 0)

static __device__ __forceinline__ ushort_t f2bf(float f) {
    unsigned u = __float_as_uint(f);
    unsigned r = (u + 0x7FFFu + ((u >> 16) & 1u)) >> 16;
    return (ushort_t)r;
}
// pack two floats to packed bf16 pair (RNE), {lo=a, hi=b}
static __device__ __forceinline__ unsigned pack2bf(float a, float b) {
    unsigned ua = __float_as_uint(a), ub = __float_as_uint(b);
    ua = ua + 0x7FFFu + ((ua >> 16) & 1u);
    ub = ub + 0x7FFFu + ((ub >> 16) & 1u);
    return (ua >> 16) | (ub & 0xFFFF0000u);
}

// async global->LDS, 16B per lane; lds dst = wave-uniform base + lane*16
static __device__ __forceinline__ void gld16(const ushort_t* g, ushort_t* l) {
    __builtin_amdgcn_global_load_lds(
        (const __attribute__((address_space(1))) void*)g,
        (__attribute__((address_space(3))) void*)l, 16, 0, 0);
}

// ---------------------------------------------------------------------------
// fp32 [rows][1024] -> bf16 [rows][1024], x | qkv_w | out_w in one launch
// ---------------------------------------------------------------------------
__global__ __launch_bounds__(256) void cvt_all(
    const float* __restrict__ x, const float* __restrict__ qw,
    const float* __restrict__ ow,
    ushort_t* __restrict__ Xc, ushort_t* __restrict__ QWc,
    ushort_t* __restrict__ OWc)
{
    const int row = blockIdx.x;
    const float* src; ushort_t* dst; int r;
    if (row < M_)            { src = x;  dst = Xc;  r = row; }
    else if (row < M_ + N3D_){ src = qw; dst = QWc; r = row - M_; }
    else                     { src = ow; dst = OWc; r = row - M_ - N3D_; }
    const int c = threadIdx.x * 4;
    float4 v = *(const float4*)(src + (size_t)r * 1024 + c);
    ushort4 hv;
    hv.x = f2bf(v.x); hv.y = f2bf(v.y); hv.z = f2bf(v.z); hv.w = f2bf(v.w);
    *(ushort4*)(dst + (size_t)r * KA + c) = hv;
}

// ---------------------------------------------------------------------------
// qkv MFMA GEMM. M=4096, N=3072, K=1024 bf16. 128x128 tile, 4 waves.
// Epilogue: Q -> Qs (pre-scaled by 0.125*log2e), K -> Khi, V -> Vt [B,H,HD,T].
// ---------------------------------------------------------------------------
__global__ __launch_bounds__(256) void qkv_mfma(
    const ushort_t* __restrict__ Ac, const ushort_t* __restrict__ Bc,
    const float* __restrict__ bias,
    ushort_t* __restrict__ Qs, ushort_t* __restrict__ Khi,
    ushort_t* __restrict__ Vt)
{
    __shared__ __align__(16) ushort_t As[16 * 512];
    __shared__ __align__(16) ushort_t Bs[16 * 512];
    const int tid = threadIdx.x;
    const int wv = tid >> 6, lane = tid & 63;
    const int l16 = lane & 15, quad = lane >> 4;
    const int wm = wv & 1, wn = wv >> 1;
    const int m0 = blockIdx.y * 128, n0 = blockIdx.x * 128;

    floatx4 acc[4][4];
#pragma unroll
    for (int i = 0; i < 4; ++i)
#pragma unroll
        for (int j = 0; j < 4; ++j) acc[i][j] = (floatx4){0.f, 0.f, 0.f, 0.f};

    for (int k0 = 0; k0 < KA; k0 += 64) {
        __syncthreads();
#pragma unroll
        for (int c = 0; c < 4; ++c) {
            const int b = wv * 4 + c;
            const int i = b >> 1, ks = b & 1;
            const int k = k0 + ks * 32 + quad * 8;
            gld16(Ac + (size_t)(m0 + i * 16 + l16) * KA + k, As + b * 512);
            gld16(Bc + (size_t)(n0 + i * 16 + l16) * KA + k, Bs + b * 512);
        }
        __syncthreads();
#pragma unroll
        for (int ks = 0; ks < 2; ++ks) {
            short8 af[4], bf[4];
#pragma unroll
            for (int ii = 0; ii < 4; ++ii)
                af[ii] = *(const short8*)(As + ((wm * 4 + ii) * 2 + ks) * 512 + lane * 8);
#pragma unroll
            for (int jj = 0; jj < 4; ++jj)
                bf[jj] = *(const short8*)(Bs + ((wn * 4 + jj) * 2 + ks) * 512 + lane * 8);
#pragma unroll
            for (int ii = 0; ii < 4; ++ii)
#pragma unroll
                for (int jj = 0; jj < 4; ++jj)
                    acc[ii][jj] = MFMA16(af[ii], bf[jj], acc[ii][jj]);
        }
    }

#pragma unroll
    for (int ii = 0; ii < 4; ++ii) {
#pragma unroll
        for (int r = 0; r < 4; ++r) {
            const int m = m0 + wm * 64 + ii * 16 + quad * 4 + r;
            const int bb = m >> 11, t = m & 2047;
#pragma unroll
            for (int jj = 0; jj < 4; ++jj) {
                const int n = n0 + wn * 64 + jj * 16 + l16;
                const int c = n >> 10, h = (n >> 6) & 15, hd = n & 63;
                const float v = acc[ii][jj][r] + bias[n];
                const size_t idx = (((size_t)bb * H_ + h) * T_ + t) * HD_ + hd;
                if (c == 0) { Qs[idx] = f2bf(v * SCALE_L2E); }
                else if (c == 1) { Khi[idx] = f2bf(v); }
                else { Vt[(((size_t)bb * H_ + h) * HD_ + hd) * T_ + t] = f2bf(v); }
            }
        }
    }
}

// ---------------------------------------------------------------------------
// out MFMA GEMM. M=4096, N=1024, K=1024. 128x64 tile (grid 512 = 2/CU).
// ---------------------------------------------------------------------------
__global__ __launch_bounds__(256) void out_mfma(
    const ushort_t* __restrict__ Ac, const ushort_t* __restrict__ Bc,
    const float* __restrict__ bias, float* __restrict__ Out)
{
    __shared__ __align__(16) ushort_t As[16 * 512];
    __shared__ __align__(16) ushort_t Bs[8 * 512];
    const int tid = threadIdx.x;
    const int wv = tid >> 6, lane = tid & 63;
    const int l16 = lane & 15, quad = lane >> 4;
    const int wm = wv & 1, wn = wv >> 1;
    const int m0 = blockIdx.y * 128, n0 = blockIdx.x * 64;

    floatx4 acc[4][2];
#pragma unroll
    for (int i = 0; i < 4; ++i)
#pragma unroll
        for (int j = 0; j < 2; ++j) acc[i][j] = (floatx4){0.f, 0.f, 0.f, 0.f};

    for (int k0 = 0; k0 < KA; k0 += 64) {
        __syncthreads();
#pragma unroll
        for (int c = 0; c < 4; ++c) {
            const int b = wv * 4 + c;
            const int i = b >> 1, ks = b & 1;
            const int k = k0 + ks * 32 + quad * 8;
            gld16(Ac + (size_t)(m0 + i * 16 + l16) * KA + k, As + b * 512);
        }
#pragma unroll
        for (int c = 0; c < 2; ++c) {
            const int b = wv * 2 + c;
            const int j = b >> 1, ks = b & 1;
            const int k = k0 + ks * 32 + quad * 8;
            gld16(Bc + (size_t)(n0 + j * 16 + l16) * KA + k, Bs + b * 512);
        }
        __syncthreads();
#pragma unroll
        for (int ks = 0; ks < 2; ++ks) {
            short8 af[4], bf[2];
#pragma unroll
            for (int ii = 0; ii < 4; ++ii)
                af[ii] = *(const short8*)(As + ((wm * 4 + ii) * 2 + ks) * 512 + lane * 8);
#pragma unroll
            for (int jj = 0; jj < 2; ++jj)
                bf[jj] = *(const short8*)(Bs + ((wn * 2 + jj) * 2 + ks) * 512 + lane * 8);
#pragma unroll
            for (int ii = 0; ii < 4; ++ii)
#pragma unroll
                for (int jj = 0; jj < 2; ++jj)
                    acc[ii][jj] = MFMA16(af[ii], bf[jj], acc[ii][jj]);
        }
    }

#pragma unroll
    for (int ii = 0; ii < 4; ++ii) {
#pragma unroll
        for (int r = 0; r < 4; ++r) {
            const int m = m0 + wm * 64 + ii * 16 + quad * 4 + r;
#pragma unroll
            for (int jj = 0; jj < 2; ++jj) {
                const int n = n0 + wn * 32 + jj * 16 + l16;
                Out[(size_t)m * D_ + n] = acc[ii][jj][r] + bias[n];
            }
        }
    }
}

// ---------------------------------------------------------------------------
// biasp[i] = dot(rel_pos[i,:], rpe_w) * log2(e)
// ---------------------------------------------------------------------------
__global__ __launch_bounds__(64) void rpe_project(
    const float* __restrict__ rel_pos, const float* __restrict__ rpe_w,
    float* __restrict__ biasp)
{
    const int i = blockIdx.x;
    const int lane = threadIdx.x;
    float v = rel_pos[(size_t)i * HD_ + lane] * rpe_w[lane];
#pragma unroll
    for (int off = 32; off; off >>= 1) v += __shfl_down(v, off);
    if (lane == 0) biasp[i] = v * L2E;
}

// ---------------------------------------------------------------------------
// Flash attention (R6 core), KV-split x2. Max-free softmax => partials
// combine exactly by addition. Each block: 16 k-tiles of one half.
// Writes unnormalized O_part (fp32) + l_part.
// Grid 2048: i&7 = XCD slot; j=i>>3: qt=j&31, split=(j>>5)&1, bh=(i&7)+8*(j>>6).
// ---------------------------------------------------------------------------
__global__ __launch_bounds__(256) void attn_mfma(
    const ushort_t* __restrict__ Qs, const ushort_t* __restrict__ Khi,
    const ushort_t* __restrict__ Vt, const float* __restrict__ biasp,
    float* __restrict__ OP, float* __restrict__ LP)
{
    __shared__ __align__(16) ushort_t KS[8 * 512];
    __shared__ __align__(16) ushort_t VS[8 * 512];
    __shared__ __align__(16) ushort_t PS[4][2 * 512];

    const int i = blockIdx.x;
    const int j = i >> 3;
    const int q0 = (j & 31) * 64;
    const int split = (j >> 5) & 1;
    const int bh = (i & 7) + 8 * (j >> 6);
    const int kbase = split * 1024;

    const int tid = threadIdx.x;
    const int wv = tid >> 6, lane = tid & 63;
    const int l16 = lane & 15, quad = lane >> 4;

    const int q = q0 + wv * 16 + l16;
    const size_t qoff = ((size_t)bh * T_ + q) * HD_ + quad * 8;
    const short8 qh0 = *(const short8*)(Qs + qoff);
    const short8 qh1 = *(const short8*)(Qs + qoff + 32);

    float l_r = 0.f;
    floatx4 o_acc[4];
#pragma unroll
    for (int g2 = 0; g2 < 4; ++g2) o_acc[g2] = (floatx4){0.f, 0.f, 0.f, 0.f};

    const ushort_t* gK = Khi + (size_t)bh * T_ * HD_;
    const ushort_t* gV = Vt + (size_t)bh * HD_ * T_;
    const int biasbase = 2047 + quad * 4 - q;

    const int qdbase = quad >> 1;
    ushort_t* pw = PS[wv];

    for (int t = 0; t < 16; ++t) {
        const int k0 = kbase + t * 64;
        __syncthreads();
        {
            const size_t krow = (size_t)(k0 + wv * 16 + l16) * HD_ + quad * 8;
            gld16(gK + krow,      KS + (wv * 2 + 0) * 512);
            gld16(gK + krow + 32, KS + (wv * 2 + 1) * 512);
            const size_t vrow = (size_t)(wv * 16 + l16) * T_ + k0 + quad * 8;
            gld16(gV + vrow,      VS + (wv * 2 + 0) * 512);
            gld16(gV + vrow + 32, VS + (wv * 2 + 1) * 512);
        }
        float4 bb[4];
#pragma unroll
        for (int g = 0; g < 4; ++g)
            __builtin_memcpy(&bb[g], biasp + (biasbase + k0 + g * 16), 16);
        __syncthreads();

        // ---- S^T = K x Q (scaled), p = exp2(s + bias) ----
#pragma unroll
        for (int g = 0; g < 4; ++g) {
            const short8 kh0 = *(const short8*)(KS + (g * 2 + 0) * 512 + lane * 8);
            const short8 kh1 = *(const short8*)(KS + (g * 2 + 1) * 512 + lane * 8);
            floatx4 a = (floatx4){0.f, 0.f, 0.f, 0.f};
            a = MFMA16(kh0, qh0, a);
            a = MFMA16(kh1, qh1, a);
            const float* bp = (const float*)&bb[g];
            float p0 = __builtin_amdgcn_exp2f(a[0] + bp[0]);
            float p1 = __builtin_amdgcn_exp2f(a[1] + bp[1]);
            float p2 = __builtin_amdgcn_exp2f(a[2] + bp[2]);
            float p3 = __builtin_amdgcn_exp2f(a[3] + bp[3]);
            l_r += (p0 + p1) + (p2 + p3);
            uint2 pkd;
            pkd.x = pack2bf(p0, p1);
            pkd.y = pack2bf(p2, p3);
            const int qd = 2 * (g & 1) + qdbase;
            *(uint2*)(pw + (g >> 1) * 512 + (qd * 16 + l16) * 8 + (quad & 1) * 4) = pkd;
        }
        const short8 p0 = *(const short8*)(pw + lane * 8);
        const short8 p1 = *(const short8*)(pw + 512 + lane * 8);

        // ---- O^T += V^T P^T ----
#pragma unroll
        for (int g2 = 0; g2 < 4; ++g2) {
            const short8 v0 = *(const short8*)(VS + (g2 * 2 + 0) * 512 + lane * 8);
            const short8 v1 = *(const short8*)(VS + (g2 * 2 + 1) * 512 + lane * 8);
            o_acc[g2] = MFMA16(v0, p0, o_acc[g2]);
            o_acc[g2] = MFMA16(v1, p1, o_acc[g2]);
        }
    }

    // ---- write unnormalized partials ----
    l_r += __shfl_xor(l_r, 16);
    l_r += __shfl_xor(l_r, 32);
    const size_t obase = (size_t)split * QE_ + ((size_t)bh * T_ + q) * HD_;
#pragma unroll
    for (int g2 = 0; g2 < 4; ++g2) {
        float4 v;
        v.x = o_acc[g2][0]; v.y = o_acc[g2][1];
        v.z = o_acc[g2][2]; v.w = o_acc[g2][3];
        *(float4*)(OP + obase + g2 * 16 + quad * 4) = v;
    }
    if (quad == 0) LP[split * (B_ * H_ * T_) + bh * T_ + q] = l_r;
}

// ---------------------------------------------------------------------------
// Combine: AO = (O0 + O1) / (l0 + l1), emit bf16 at [b*T+t][h*64+hd].
// One thread per 4 hd elems. Grid 4096 x 256.
// ---------------------------------------------------------------------------
__global__ __launch_bounds__(256) void attn_combine(
    const float* __restrict__ OP, const float* __restrict__ LP,
    ushort_t* __restrict__ AOc)
{
    const int flat = blockIdx.x * 256 + threadIdx.x;
    const int bh = flat >> 15;
    const int rem = flat & 32767;
    const int q = rem >> 4;
    const int hd4 = (rem & 15) * 4;
    const size_t base = ((size_t)bh * T_ + q) * HD_ + hd4;
    float4 a = *(const float4*)(OP + base);
    float4 b = *(const float4*)(OP + (size_t)QE_ + base);
    const float l = LP[bh * T_ + q] + LP[B_ * H_ * T_ + bh * T_ + q];
    const float inv = 1.0f / l;
    uint2 pk;
    pk.x = pack2bf((a.x + b.x) * inv, (a.y + b.y) * inv);
    pk.y = pack2bf((a.z + b.z) * inv, (a.w + b.w) * inv);
    const int bb = bh >> 4, h2 = bh & 15;
    *(uint2*)(AOc + ((size_t)bb * T_ + q) * KA + h2 * 64 + hd4) = pk;
}

// ---------------------------------------------------------------------------
extern "C" void kernel_launch(void* const* d_in, const int* in_sizes, int n_in,
                              void* d_out, int out_size, void* d_ws, size_t ws_size,
                              hipStream_t stream)
{
    const float* x       = (const float*)d_in[0];
    const float* qkv_w   = (const float*)d_in[1];
    const float* qkv_b   = (const float*)d_in[2];
    const float* out_w   = (const float*)d_in[3];
    const float* out_b   = (const float*)d_in[4];
    const float* rel_pos = (const float*)d_in[5];
    const float* rpe_w   = (const float*)d_in[6];
    float* out = (float*)d_out;

    const size_t QE = QE_;  // 4,194,304
    ushort_t* Qs  = (ushort_t*)d_ws;
    ushort_t* Khi = Qs  + QE;
    ushort_t* Vt  = Khi + QE;
    ushort_t* Xc  = Vt  + QE;                  // [4096][1024]
    ushort_t* QWc = Xc  + (size_t)M_ * KA;     // [3072][1024]
    ushort_t* OWc = QWc + (size_t)N3D_ * KA;   // [1024][1024]
    ushort_t* AOc = OWc + (size_t)D_ * KA;     // [4096][1024]
    float* biasp  = (float*)(AOc + (size_t)M_ * KA);
    float* OP     = biasp + 4352;              // [2][QE] fp32 partials
    float* LP     = OP + 2 * QE;               // [2][B*H*T] fp32 l partials

    cvt_all<<<M_ + N3D_ + D_, 256, 0, stream>>>(x, qkv_w, out_w, Xc, QWc, OWc);
    rpe_project<<<2 * MAXLEN_ - 1, 64, 0, stream>>>(rel_pos, rpe_w, biasp);

    qkv_mfma<<<dim3(N3D_ / 128, M_ / 128), 256, 0, stream>>>(
        Xc, QWc, qkv_b, Qs, Khi, Vt);
    attn_mfma<<<2048, 256, 0, stream>>>(Qs, Khi, Vt, biasp, OP, LP);
    attn_combine<<<4096, 256, 0, stream>>>(OP, LP, AOc);
    out_mfma<<<dim3(D_ / 64, M_ / 128), 256, 0, stream>>>(
        AOc, OWc, out_b, out);
}

// Round 9
// 277.952 us; speedup vs baseline: 1.3570x; 1.0655x over previous
//
#include <hip/hip_runtime.h>
#include <math.h>

#define B_ 2
#define T_ 2048
#define D_ 1024
#define H_ 16
#define HD_ 64
#define MAXLEN_ 2048
#define N3D_ 3072
#define M_ (B_ * T_)   // 4096
#define KA 1024        // GEMM K (plain bf16)

#define SCALE_L2E 0.18033688011116215f   // 0.125 * log2(e)
#define L2E 1.4426950408889634f

typedef unsigned short ushort_t;
typedef __attribute__((ext_vector_type(8))) short short8;
typedef __attribute__((ext_vector_type(4))) float floatx4;
#define MFMA16(a, b, c) __builtin_amdgcn_mfma_f32_16x16x32_bf16(a, b, c, 0, 0, 0)

static __device__ __forceinline__ ushort_t f2bf(float f) {
    unsigned u = __float_as_uint(f);
    unsigned r = (u + 0x7FFFu + ((u >> 16) & 1u)) >> 16;
    return (ushort_t)r;
}
// pack two floats to packed bf16 pair (RNE), {lo=a, hi=b}
static __device__ __forceinline__ unsigned pack2bf(float a, float b) {
    unsigned ua = __float_as_uint(a), ub = __float_as_uint(b);
    ua = ua + 0x7FFFu + ((ua >> 16) & 1u);
    ub = ub + 0x7FFFu + ((ub >> 16) & 1u);
    return (ua >> 16) | (ub & 0xFFFF0000u);
}

// async global->LDS, 16B per lane; lds dst = wave-uniform base + lane*16
static __device__ __forceinline__ void gld16(const ushort_t* g, ushort_t* l) {
    __builtin_amdgcn_global_load_lds(
        (const __attribute__((address_space(1))) void*)g,
        (__attribute__((address_space(3))) void*)l, 16, 0, 0);
}

// ---------------------------------------------------------------------------
// fp32 [rows][1024] -> bf16 [rows][1024], x | qkv_w | out_w in one launch
// ---------------------------------------------------------------------------
__global__ __launch_bounds__(256) void cvt_all(
    const float* __restrict__ x, const float* __restrict__ qw,
    const float* __restrict__ ow,
    ushort_t* __restrict__ Xc, ushort_t* __restrict__ QWc,
    ushort_t* __restrict__ OWc)
{
    const int row = blockIdx.x;
    const float* src; ushort_t* dst; int r;
    if (row < M_)            { src = x;  dst = Xc;  r = row; }
    else if (row < M_ + N3D_){ src = qw; dst = QWc; r = row - M_; }
    else                     { src = ow; dst = OWc; r = row - M_ - N3D_; }
    const int c = threadIdx.x * 4;
    float4 v = *(const float4*)(src + (size_t)r * 1024 + c);
    ushort4 hv;
    hv.x = f2bf(v.x); hv.y = f2bf(v.y); hv.z = f2bf(v.z); hv.w = f2bf(v.w);
    *(ushort4*)(dst + (size_t)r * KA + c) = hv;
}

// ---------------------------------------------------------------------------
// qkv MFMA GEMM. M=4096, N=3072, K=1024 bf16. 128x128 tile, 4 waves.
// Epilogue: Q -> Qs (pre-scaled by 0.125*log2e), K -> Khi, V -> Vt [B,H,HD,T].
// ---------------------------------------------------------------------------
__global__ __launch_bounds__(256) void qkv_mfma(
    const ushort_t* __restrict__ Ac, const ushort_t* __restrict__ Bc,
    const float* __restrict__ bias,
    ushort_t* __restrict__ Qs, ushort_t* __restrict__ Khi,
    ushort_t* __restrict__ Vt)
{
    __shared__ __align__(16) ushort_t As[16 * 512];
    __shared__ __align__(16) ushort_t Bs[16 * 512];
    const int tid = threadIdx.x;
    const int wv = tid >> 6, lane = tid & 63;
    const int l16 = lane & 15, quad = lane >> 4;
    const int wm = wv & 1, wn = wv >> 1;
    const int m0 = blockIdx.y * 128, n0 = blockIdx.x * 128;

    floatx4 acc[4][4];
#pragma unroll
    for (int i = 0; i < 4; ++i)
#pragma unroll
        for (int j = 0; j < 4; ++j) acc[i][j] = (floatx4){0.f, 0.f, 0.f, 0.f};

    for (int k0 = 0; k0 < KA; k0 += 64) {
        __syncthreads();
#pragma unroll
        for (int c = 0; c < 4; ++c) {
            const int b = wv * 4 + c;
            const int i = b >> 1, ks = b & 1;
            const int k = k0 + ks * 32 + quad * 8;
            gld16(Ac + (size_t)(m0 + i * 16 + l16) * KA + k, As + b * 512);
            gld16(Bc + (size_t)(n0 + i * 16 + l16) * KA + k, Bs + b * 512);
        }
        __syncthreads();
#pragma unroll
        for (int ks = 0; ks < 2; ++ks) {
            short8 af[4], bf[4];
#pragma unroll
            for (int ii = 0; ii < 4; ++ii)
                af[ii] = *(const short8*)(As + ((wm * 4 + ii) * 2 + ks) * 512 + lane * 8);
#pragma unroll
            for (int jj = 0; jj < 4; ++jj)
                bf[jj] = *(const short8*)(Bs + ((wn * 4 + jj) * 2 + ks) * 512 + lane * 8);
#pragma unroll
            for (int ii = 0; ii < 4; ++ii)
#pragma unroll
                for (int jj = 0; jj < 4; ++jj)
                    acc[ii][jj] = MFMA16(af[ii], bf[jj], acc[ii][jj]);
        }
    }

#pragma unroll
    for (int ii = 0; ii < 4; ++ii) {
#pragma unroll
        for (int r = 0; r < 4; ++r) {
            const int m = m0 + wm * 64 + ii * 16 + quad * 4 + r;
            const int bb = m >> 11, t = m & 2047;
#pragma unroll
            for (int jj = 0; jj < 4; ++jj) {
                const int n = n0 + wn * 64 + jj * 16 + l16;
                const int c = n >> 10, h = (n >> 6) & 15, hd = n & 63;
                const float v = acc[ii][jj][r] + bias[n];
                const size_t idx = (((size_t)bb * H_ + h) * T_ + t) * HD_ + hd;
                if (c == 0) { Qs[idx] = f2bf(v * SCALE_L2E); }
                else if (c == 1) { Khi[idx] = f2bf(v); }
                else { Vt[(((size_t)bb * H_ + h) * HD_ + hd) * T_ + t] = f2bf(v); }
            }
        }
    }
}

// ---------------------------------------------------------------------------
// out MFMA GEMM. M=4096, N=1024, K=1024. 128x64 tile (grid 512 = 2/CU).
// ---------------------------------------------------------------------------
__global__ __launch_bounds__(256) void out_mfma(
    const ushort_t* __restrict__ Ac, const ushort_t* __restrict__ Bc,
    const float* __restrict__ bias, float* __restrict__ Out)
{
    __shared__ __align__(16) ushort_t As[16 * 512];
    __shared__ __align__(16) ushort_t Bs[8 * 512];
    const int tid = threadIdx.x;
    const int wv = tid >> 6, lane = tid & 63;
    const int l16 = lane & 15, quad = lane >> 4;
    const int wm = wv & 1, wn = wv >> 1;
    const int m0 = blockIdx.y * 128, n0 = blockIdx.x * 64;

    floatx4 acc[4][2];
#pragma unroll
    for (int i = 0; i < 4; ++i)
#pragma unroll
        for (int j = 0; j < 2; ++j) acc[i][j] = (floatx4){0.f, 0.f, 0.f, 0.f};

    for (int k0 = 0; k0 < KA; k0 += 64) {
        __syncthreads();
#pragma unroll
        for (int c = 0; c < 4; ++c) {
            const int b = wv * 4 + c;
            const int i = b >> 1, ks = b & 1;
            const int k = k0 + ks * 32 + quad * 8;
            gld16(Ac + (size_t)(m0 + i * 16 + l16) * KA + k, As + b * 512);
        }
#pragma unroll
        for (int c = 0; c < 2; ++c) {
            const int b = wv * 2 + c;
            const int j = b >> 1, ks = b & 1;
            const int k = k0 + ks * 32 + quad * 8;
            gld16(Bc + (size_t)(n0 + j * 16 + l16) * KA + k, Bs + b * 512);
        }
        __syncthreads();
#pragma unroll
        for (int ks = 0; ks < 2; ++ks) {
            short8 af[4], bf[2];
#pragma unroll
            for (int ii = 0; ii < 4; ++ii)
                af[ii] = *(const short8*)(As + ((wm * 4 + ii) * 2 + ks) * 512 + lane * 8);
#pragma unroll
            for (int jj = 0; jj < 2; ++jj)
                bf[jj] = *(const short8*)(Bs + ((wn * 2 + jj) * 2 + ks) * 512 + lane * 8);
#pragma unroll
            for (int ii = 0; ii < 4; ++ii)
#pragma unroll
                for (int jj = 0; jj < 2; ++jj)
                    acc[ii][jj] = MFMA16(af[ii], bf[jj], acc[ii][jj]);
        }
    }

#pragma unroll
    for (int ii = 0; ii < 4; ++ii) {
#pragma unroll
        for (int r = 0; r < 4; ++r) {
            const int m = m0 + wm * 64 + ii * 16 + quad * 4 + r;
#pragma unroll
            for (int jj = 0; jj < 2; ++jj) {
                const int n = n0 + wn * 32 + jj * 16 + l16;
                Out[(size_t)m * D_ + n] = acc[ii][jj][r] + bias[n];
            }
        }
    }
}

// ---------------------------------------------------------------------------
// biasp[i] = dot(rel_pos[i,:], rpe_w) * log2(e)
// ---------------------------------------------------------------------------
__global__ __launch_bounds__(64) void rpe_project(
    const float* __restrict__ rel_pos, const float* __restrict__ rpe_w,
    float* __restrict__ biasp)
{
    const int i = blockIdx.x;
    const int lane = threadIdx.x;
    float v = rel_pos[(size_t)i * HD_ + lane] * rpe_w[lane];
#pragma unroll
    for (int off = 32; off; off >>= 1) v += __shfl_down(v, off);
    if (lane == 0) biasp[i] = v * L2E;
}

// ---------------------------------------------------------------------------
// Flash attention (R6 core) + double-buffered K/V staging.
// Loop: issue gld16(t+1 -> buf^1) -> compute(buf) -> one __syncthreads().
// The vmcnt(0) drain at the barrier now covers a prefetch that has had the
// whole compute phase to land -> staging latency off the critical path.
// Max-free softmax, XCD-swizzled grid (1024 blocks, 4/CU).
// ---------------------------------------------------------------------------
__global__ __launch_bounds__(256) void attn_mfma(
    const ushort_t* __restrict__ Qs, const ushort_t* __restrict__ Khi,
    const ushort_t* __restrict__ Vt, const float* __restrict__ biasp,
    ushort_t* __restrict__ AOc)
{
    __shared__ __align__(16) ushort_t KS[2][8 * 512];
    __shared__ __align__(16) ushort_t VS[2][8 * 512];
    __shared__ __align__(16) ushort_t PS[4][2 * 512];

    const int i = blockIdx.x;
    const int bh = (i & 7) + 8 * (i >> 8);
    const int q0 = ((i >> 3) & 31) * 64;
    const int tid = threadIdx.x;
    const int wv = tid >> 6, lane = tid & 63;
    const int l16 = lane & 15, quad = lane >> 4;

    const int q = q0 + wv * 16 + l16;
    const size_t qoff = ((size_t)bh * T_ + q) * HD_ + quad * 8;
    const short8 qh0 = *(const short8*)(Qs + qoff);
    const short8 qh1 = *(const short8*)(Qs + qoff + 32);

    float l_r = 0.f;
    floatx4 o_acc[4];
#pragma unroll
    for (int g2 = 0; g2 < 4; ++g2) o_acc[g2] = (floatx4){0.f, 0.f, 0.f, 0.f};

    const ushort_t* gK = Khi + (size_t)bh * T_ * HD_;
    const ushort_t* gV = Vt + (size_t)bh * HD_ * T_;
    const int biasbase = 2047 + quad * 4 - q;

    const int qdbase = quad >> 1;
    ushort_t* pw = PS[wv];

    // stage-in address components (per lane, fixed)
    const size_t kstage = (size_t)(wv * 16 + l16) * HD_ + quad * 8;
    const size_t vstage = (size_t)(wv * 16 + l16) * T_ + quad * 8;

    // ---- prologue: stage tile 0 into buffer 0 ----
    gld16(gK + kstage,              KS[0] + (wv * 2 + 0) * 512);
    gld16(gK + kstage + 32,         KS[0] + (wv * 2 + 1) * 512);
    gld16(gV + vstage,              VS[0] + (wv * 2 + 0) * 512);
    gld16(gV + vstage + 32,         VS[0] + (wv * 2 + 1) * 512);
    __syncthreads();

    for (int t = 0; t < 32; ++t) {
        const int k0 = t * 64;
        const int buf = t & 1, nbuf = buf ^ 1;

        // ---- prefetch tile t+1 into the other buffer ----
        if (t < 31) {
            const size_t koff = kstage + (size_t)(k0 + 64) * HD_;
            gld16(gK + koff,      KS[nbuf] + (wv * 2 + 0) * 512);
            gld16(gK + koff + 32, KS[nbuf] + (wv * 2 + 1) * 512);
            const size_t voff = vstage + (size_t)(k0 + 64);
            gld16(gV + voff,      VS[nbuf] + (wv * 2 + 0) * 512);
            gld16(gV + voff + 32, VS[nbuf] + (wv * 2 + 1) * 512);
        }
        float4 bb[4];
#pragma unroll
        for (int g = 0; g < 4; ++g)
            __builtin_memcpy(&bb[g], biasp + (biasbase + k0 + g * 16), 16);

        // ---- S^T = K x Q (scaled), p = exp2(s + bias) ----
#pragma unroll
        for (int g = 0; g < 4; ++g) {
            const short8 kh0 = *(const short8*)(KS[buf] + (g * 2 + 0) * 512 + lane * 8);
            const short8 kh1 = *(const short8*)(KS[buf] + (g * 2 + 1) * 512 + lane * 8);
            floatx4 a = (floatx4){0.f, 0.f, 0.f, 0.f};
            a = MFMA16(kh0, qh0, a);
            a = MFMA16(kh1, qh1, a);
            const float* bp = (const float*)&bb[g];
            float p0 = __builtin_amdgcn_exp2f(a[0] + bp[0]);
            float p1 = __builtin_amdgcn_exp2f(a[1] + bp[1]);
            float p2 = __builtin_amdgcn_exp2f(a[2] + bp[2]);
            float p3 = __builtin_amdgcn_exp2f(a[3] + bp[3]);
            l_r += (p0 + p1) + (p2 + p3);
            uint2 pkd;
            pkd.x = pack2bf(p0, p1);
            pkd.y = pack2bf(p2, p3);
            const int qd = 2 * (g & 1) + qdbase;
            *(uint2*)(pw + (g >> 1) * 512 + (qd * 16 + l16) * 8 + (quad & 1) * 4) = pkd;
        }
        const short8 p0 = *(const short8*)(pw + lane * 8);
        const short8 p1 = *(const short8*)(pw + 512 + lane * 8);

        // ---- O^T += V^T P^T ----
#pragma unroll
        for (int g2 = 0; g2 < 4; ++g2) {
            const short8 v0 = *(const short8*)(VS[buf] + (g2 * 2 + 0) * 512 + lane * 8);
            const short8 v1 = *(const short8*)(VS[buf] + (g2 * 2 + 1) * 512 + lane * 8);
            o_acc[g2] = MFMA16(v0, p0, o_acc[g2]);
            o_acc[g2] = MFMA16(v1, p1, o_acc[g2]);
        }
        __syncthreads();
    }

    // ---- deferred l reduction + epilogue ----
    l_r += __shfl_xor(l_r, 16);
    l_r += __shfl_xor(l_r, 32);
    const float inv = 1.0f / l_r;
    const int bb2 = bh >> 4, h2 = bh & 15;
    const size_t m = (size_t)bb2 * T_ + q;
#pragma unroll
    for (int g2 = 0; g2 < 4; ++g2) {
        uint2 pk;
        pk.x = pack2bf(o_acc[g2][0] * inv, o_acc[g2][1] * inv);
        pk.y = pack2bf(o_acc[g2][2] * inv, o_acc[g2][3] * inv);
        *(uint2*)(AOc + m * KA + h2 * 64 + g2 * 16 + quad * 4) = pk;
    }
}

// ---------------------------------------------------------------------------
extern "C" void kernel_launch(void* const* d_in, const int* in_sizes, int n_in,
                              void* d_out, int out_size, void* d_ws, size_t ws_size,
                              hipStream_t stream)
{
    const float* x       = (const float*)d_in[0];
    const float* qkv_w   = (const float*)d_in[1];
    const float* qkv_b   = (const float*)d_in[2];
    const float* out_w   = (const float*)d_in[3];
    const float* out_b   = (const float*)d_in[4];
    const float* rel_pos = (const float*)d_in[5];
    const float* rpe_w   = (const float*)d_in[6];
    float* out = (float*)d_out;

    const size_t QE = (size_t)B_ * H_ * T_ * HD_;  // 4,194,304
    ushort_t* Qs  = (ushort_t*)d_ws;
    ushort_t* Khi = Qs  + QE;
    ushort_t* Vt  = Khi + QE;
    ushort_t* Xc  = Vt  + QE;                  // [4096][1024]
    ushort_t* QWc = Xc  + (size_t)M_ * KA;     // [3072][1024]
    ushort_t* OWc = QWc + (size_t)N3D_ * KA;   // [1024][1024]
    ushort_t* AOc = OWc + (size_t)D_ * KA;     // [4096][1024]
    float* biasp  = (float*)(AOc + (size_t)M_ * KA);

    cvt_all<<<M_ + N3D_ + D_, 256, 0, stream>>>(x, qkv_w, out_w, Xc, QWc, OWc);
    rpe_project<<<2 * MAXLEN_ - 1, 64, 0, stream>>>(rel_pos, rpe_w, biasp);

    qkv_mfma<<<dim3(N3D_ / 128, M_ / 128), 256, 0, stream>>>(
        Xc, QWc, qkv_b, Qs, Khi, Vt);
    attn_mfma<<<1024, 256, 0, stream>>>(Qs, Khi, Vt, biasp, AOc);
    out_mfma<<<dim3(D_ / 64, M_ / 128), 256, 0, stream>>>(
        AOc, OWc, out_b, out);
}

// Round 10
// 272.514 us; speedup vs baseline: 1.3841x; 1.0200x over previous
//
#include <hip/hip_runtime.h>
#include <math.h>

#define B_ 2
#define T_ 2048
#define D_ 1024
#define H_ 16
#define HD_ 64
#define MAXLEN_ 2048
#define N3D_ 3072
#define M_ (B_ * T_)   // 4096
#define KA 1024        // GEMM K (plain bf16)

#define SCALE_L2E 0.18033688011116215f   // 0.125 * log2(e)
#define L2E 1.4426950408889634f

typedef unsigned short ushort_t;
typedef __attribute__((ext_vector_type(8))) short short8;
typedef __attribute__((ext_vector_type(4))) float floatx4;
#define MFMA16(a, b, c) __builtin_amdgcn_mfma_f32_16x16x32_bf16(a, b, c, 0, 0, 0)

static __device__ __forceinline__ ushort_t f2bf(float f) {
    unsigned u = __float_as_uint(f);
    unsigned r = (u + 0x7FFFu + ((u >> 16) & 1u)) >> 16;
    return (ushort_t)r;
}
// round-half-up bf16 pair pack: add 0x8000 then take hi16 of each via v_perm.
// (differs from RNE only on exact-tie mantissas; statistically negligible)
static __device__ __forceinline__ unsigned packrnu(float a, float b) {
    unsigned ua = __float_as_uint(a) + 0x8000u;
    unsigned ub = __float_as_uint(b) + 0x8000u;
    return __builtin_amdgcn_perm(ub, ua, 0x07060302u);
}

// async global->LDS, 16B per lane; lds dst = wave-uniform base + lane*16
static __device__ __forceinline__ void gld16(const ushort_t* g, ushort_t* l) {
    __builtin_amdgcn_global_load_lds(
        (const __attribute__((address_space(1))) void*)g,
        (__attribute__((address_space(3))) void*)l, 16, 0, 0);
}

// ---------------------------------------------------------------------------
// Fused precompute: rows [0, 8192) convert x|qkv_w|out_w fp32->bf16;
// rows [8192, 9216) project rel_pos @ rpe_w (4 rows/block, 1 per wave).
// ---------------------------------------------------------------------------
__global__ __launch_bounds__(256) void cvt_all(
    const float* __restrict__ x, const float* __restrict__ qw,
    const float* __restrict__ ow, const float* __restrict__ rel_pos,
    const float* __restrict__ rpe_w,
    ushort_t* __restrict__ Xc, ushort_t* __restrict__ QWc,
    ushort_t* __restrict__ OWc, float* __restrict__ biasp)
{
    const int row = blockIdx.x;
    if (row < M_ + N3D_ + D_) {
        const float* src; ushort_t* dst; int r;
        if (row < M_)            { src = x;  dst = Xc;  r = row; }
        else if (row < M_ + N3D_){ src = qw; dst = QWc; r = row - M_; }
        else                     { src = ow; dst = OWc; r = row - M_ - N3D_; }
        const int c = threadIdx.x * 4;
        float4 v = *(const float4*)(src + (size_t)r * 1024 + c);
        ushort4 hv;
        hv.x = f2bf(v.x); hv.y = f2bf(v.y); hv.z = f2bf(v.z); hv.w = f2bf(v.w);
        *(ushort4*)(dst + (size_t)r * KA + c) = hv;
    } else {
        const int wv = threadIdx.x >> 6, lane = threadIdx.x & 63;
        const int r = (row - (M_ + N3D_ + D_)) * 4 + wv;
        if (r < 2 * MAXLEN_ - 1) {
            float v = rel_pos[(size_t)r * HD_ + lane] * rpe_w[lane];
#pragma unroll
            for (int off = 32; off; off >>= 1) v += __shfl_down(v, off);
            if (lane == 0) biasp[r] = v * L2E;
        }
    }
}

// ---------------------------------------------------------------------------
// qkv MFMA GEMM. M=4096, N=3072, K=1024 bf16. 128x128 tile, 4 waves.
// Epilogue: Q -> Qs (pre-scaled by 0.125*log2e), K -> Khi, V -> Vt [B,H,HD,T].
// ---------------------------------------------------------------------------
__global__ __launch_bounds__(256) void qkv_mfma(
    const ushort_t* __restrict__ Ac, const ushort_t* __restrict__ Bc,
    const float* __restrict__ bias,
    ushort_t* __restrict__ Qs, ushort_t* __restrict__ Khi,
    ushort_t* __restrict__ Vt)
{
    __shared__ __align__(16) ushort_t As[16 * 512];
    __shared__ __align__(16) ushort_t Bs[16 * 512];
    const int tid = threadIdx.x;
    const int wv = tid >> 6, lane = tid & 63;
    const int l16 = lane & 15, quad = lane >> 4;
    const int wm = wv & 1, wn = wv >> 1;
    const int m0 = blockIdx.y * 128, n0 = blockIdx.x * 128;

    floatx4 acc[4][4];
#pragma unroll
    for (int i = 0; i < 4; ++i)
#pragma unroll
        for (int j = 0; j < 4; ++j) acc[i][j] = (floatx4){0.f, 0.f, 0.f, 0.f};

    for (int k0 = 0; k0 < KA; k0 += 64) {
        __syncthreads();
#pragma unroll
        for (int c = 0; c < 4; ++c) {
            const int b = wv * 4 + c;
            const int i = b >> 1, ks = b & 1;
            const int k = k0 + ks * 32 + quad * 8;
            gld16(Ac + (size_t)(m0 + i * 16 + l16) * KA + k, As + b * 512);
            gld16(Bc + (size_t)(n0 + i * 16 + l16) * KA + k, Bs + b * 512);
        }
        __syncthreads();
#pragma unroll
        for (int ks = 0; ks < 2; ++ks) {
            short8 af[4], bf[4];
#pragma unroll
            for (int ii = 0; ii < 4; ++ii)
                af[ii] = *(const short8*)(As + ((wm * 4 + ii) * 2 + ks) * 512 + lane * 8);
#pragma unroll
            for (int jj = 0; jj < 4; ++jj)
                bf[jj] = *(const short8*)(Bs + ((wn * 4 + jj) * 2 + ks) * 512 + lane * 8);
#pragma unroll
            for (int ii = 0; ii < 4; ++ii)
#pragma unroll
                for (int jj = 0; jj < 4; ++jj)
                    acc[ii][jj] = MFMA16(af[ii], bf[jj], acc[ii][jj]);
        }
    }

#pragma unroll
    for (int ii = 0; ii < 4; ++ii) {
#pragma unroll
        for (int r = 0; r < 4; ++r) {
            const int m = m0 + wm * 64 + ii * 16 + quad * 4 + r;
            const int bb = m >> 11, t = m & 2047;
#pragma unroll
            for (int jj = 0; jj < 4; ++jj) {
                const int n = n0 + wn * 64 + jj * 16 + l16;
                const int c = n >> 10, h = (n >> 6) & 15, hd = n & 63;
                const float v = acc[ii][jj][r] + bias[n];
                const size_t idx = (((size_t)bb * H_ + h) * T_ + t) * HD_ + hd;
                if (c == 0) { Qs[idx] = f2bf(v * SCALE_L2E); }
                else if (c == 1) { Khi[idx] = f2bf(v); }
                else { Vt[(((size_t)bb * H_ + h) * HD_ + hd) * T_ + t] = f2bf(v); }
            }
        }
    }
}

// ---------------------------------------------------------------------------
// out MFMA GEMM. M=4096, N=1024, K=1024. 128x64 tile (grid 512 = 2/CU).
// ---------------------------------------------------------------------------
__global__ __launch_bounds__(256) void out_mfma(
    const ushort_t* __restrict__ Ac, const ushort_t* __restrict__ Bc,
    const float* __restrict__ bias, float* __restrict__ Out)
{
    __shared__ __align__(16) ushort_t As[16 * 512];
    __shared__ __align__(16) ushort_t Bs[8 * 512];
    const int tid = threadIdx.x;
    const int wv = tid >> 6, lane = tid & 63;
    const int l16 = lane & 15, quad = lane >> 4;
    const int wm = wv & 1, wn = wv >> 1;
    const int m0 = blockIdx.y * 128, n0 = blockIdx.x * 64;

    floatx4 acc[4][2];
#pragma unroll
    for (int i = 0; i < 4; ++i)
#pragma unroll
        for (int j = 0; j < 2; ++j) acc[i][j] = (floatx4){0.f, 0.f, 0.f, 0.f};

    for (int k0 = 0; k0 < KA; k0 += 64) {
        __syncthreads();
#pragma unroll
        for (int c = 0; c < 4; ++c) {
            const int b = wv * 4 + c;
            const int i = b >> 1, ks = b & 1;
            const int k = k0 + ks * 32 + quad * 8;
            gld16(Ac + (size_t)(m0 + i * 16 + l16) * KA + k, As + b * 512);
        }
#pragma unroll
        for (int c = 0; c < 2; ++c) {
            const int b = wv * 2 + c;
            const int j = b >> 1, ks = b & 1;
            const int k = k0 + ks * 32 + quad * 8;
            gld16(Bc + (size_t)(n0 + j * 16 + l16) * KA + k, Bs + b * 512);
        }
        __syncthreads();
#pragma unroll
        for (int ks = 0; ks < 2; ++ks) {
            short8 af[4], bf[2];
#pragma unroll
            for (int ii = 0; ii < 4; ++ii)
                af[ii] = *(const short8*)(As + ((wm * 4 + ii) * 2 + ks) * 512 + lane * 8);
#pragma unroll
            for (int jj = 0; jj < 2; ++jj)
                bf[jj] = *(const short8*)(Bs + ((wn * 2 + jj) * 2 + ks) * 512 + lane * 8);
#pragma unroll
            for (int ii = 0; ii < 4; ++ii)
#pragma unroll
                for (int jj = 0; jj < 2; ++jj)
                    acc[ii][jj] = MFMA16(af[ii], bf[jj], acc[ii][jj]);
        }
    }

#pragma unroll
    for (int ii = 0; ii < 4; ++ii) {
#pragma unroll
        for (int r = 0; r < 4; ++r) {
            const int m = m0 + wm * 64 + ii * 16 + quad * 4 + r;
#pragma unroll
            for (int jj = 0; jj < 2; ++jj) {
                const int n = n0 + wn * 32 + jj * 16 + l16;
                Out[(size_t)m * D_ + n] = acc[ii][jj][r] + bias[n];
            }
        }
    }
}

// ---------------------------------------------------------------------------
// Flash attention v4: S^T formulation, 32 q-columns per wave (2x16 groups),
// q-tile 128/block, grid 512 (2 blocks/CU). K/V frag reads amortized across
// both q-groups. Double-buffered K/V staging, max-free softmax, XCD swizzle.
// ---------------------------------------------------------------------------
__global__ __launch_bounds__(256) void attn_mfma(
    const ushort_t* __restrict__ Qs, const ushort_t* __restrict__ Khi,
    const ushort_t* __restrict__ Vt, const float* __restrict__ biasp,
    ushort_t* __restrict__ AOc)
{
    __shared__ __align__(16) ushort_t KS[2][8 * 512];   // 16 KB
    __shared__ __align__(16) ushort_t VS[2][8 * 512];   // 16 KB
    __shared__ __align__(16) ushort_t PS[4][2][1024];   // 16 KB: wave, qgroup

    // XCD swizzle: 16 q-tiles of one bh stay on one XCD slot
    const int i = blockIdx.x;
    const int j = i >> 3;
    const int bh = (i & 7) + 8 * (j >> 4);
    const int q0 = (j & 15) * 128;
    const int tid = threadIdx.x;
    const int wv = tid >> 6, lane = tid & 63;
    const int l16 = lane & 15, quad = lane >> 4;

    const int qw = q0 + wv * 32;

    // Q B-fragments for the wave's two 16-col groups (persistent)
    short8 qh[2][2];
#pragma unroll
    for (int u = 0; u < 2; ++u) {
        const size_t qoff = ((size_t)bh * T_ + qw + u * 16 + l16) * HD_ + quad * 8;
        qh[u][0] = *(const short8*)(Qs + qoff);
        qh[u][1] = *(const short8*)(Qs + qoff + 32);
    }

    float l_r[2] = {0.f, 0.f};
    floatx4 o_acc[4][2];
#pragma unroll
    for (int g2 = 0; g2 < 4; ++g2)
#pragma unroll
        for (int u = 0; u < 2; ++u) o_acc[g2][u] = (floatx4){0.f, 0.f, 0.f, 0.f};

    const ushort_t* gK = Khi + (size_t)bh * T_ * HD_;
    const ushort_t* gV = Vt + (size_t)bh * HD_ * T_;
    const int bias_u[2] = {2047 + quad * 4 - (qw + l16),
                           2047 + quad * 4 - (qw + 16 + l16)};
    const int qdbase = quad >> 1;

    const size_t kstage = (size_t)(wv * 16 + l16) * HD_ + quad * 8;
    const size_t vstage = (size_t)(wv * 16 + l16) * T_ + quad * 8;

    // prologue: stage tile 0 into buffer 0
    gld16(gK + kstage,      KS[0] + (wv * 2 + 0) * 512);
    gld16(gK + kstage + 32, KS[0] + (wv * 2 + 1) * 512);
    gld16(gV + vstage,      VS[0] + (wv * 2 + 0) * 512);
    gld16(gV + vstage + 32, VS[0] + (wv * 2 + 1) * 512);
    __syncthreads();

    for (int t = 0; t < 32; ++t) {
        const int k0 = t * 64;
        const int buf = t & 1, nbuf = buf ^ 1;

        if (t < 31) {
            const size_t koff = kstage + (size_t)(k0 + 64) * HD_;
            gld16(gK + koff,      KS[nbuf] + (wv * 2 + 0) * 512);
            gld16(gK + koff + 32, KS[nbuf] + (wv * 2 + 1) * 512);
            const size_t voff = vstage + (size_t)(k0 + 64);
            gld16(gV + voff,      VS[nbuf] + (wv * 2 + 0) * 512);
            gld16(gV + voff + 32, VS[nbuf] + (wv * 2 + 1) * 512);
        }

        // ---- S^T = K x Q (both q-groups share K frags); p = exp2(s+bias) ----
#pragma unroll
        for (int g = 0; g < 4; ++g) {
            const short8 kh0 = *(const short8*)(KS[buf] + (g * 2 + 0) * 512 + lane * 8);
            const short8 kh1 = *(const short8*)(KS[buf] + (g * 2 + 1) * 512 + lane * 8);
            const int qd = 2 * (g & 1) + qdbase;
#pragma unroll
            for (int u = 0; u < 2; ++u) {
                floatx4 a = (floatx4){0.f, 0.f, 0.f, 0.f};
                a = MFMA16(kh0, qh[u][0], a);
                a = MFMA16(kh1, qh[u][1], a);
                float4 bb;
                __builtin_memcpy(&bb, biasp + (bias_u[u] + k0 + g * 16), 16);
                const float p0 = __builtin_amdgcn_exp2f(a[0] + bb.x);
                const float p1 = __builtin_amdgcn_exp2f(a[1] + bb.y);
                const float p2 = __builtin_amdgcn_exp2f(a[2] + bb.z);
                const float p3 = __builtin_amdgcn_exp2f(a[3] + bb.w);
                l_r[u] += (p0 + p1) + (p2 + p3);
                uint2 pkd;
                pkd.x = packrnu(p0, p1);
                pkd.y = packrnu(p2, p3);
                *(uint2*)(PS[wv][u] + (g >> 1) * 512 + (qd * 16 + l16) * 8 + (quad & 1) * 4) = pkd;
            }
        }

        // ---- P frag reads (wave-internal dependency) ----
        short8 pf[2][2];
#pragma unroll
        for (int u = 0; u < 2; ++u) {
            pf[u][0] = *(const short8*)(PS[wv][u] + lane * 8);
            pf[u][1] = *(const short8*)(PS[wv][u] + 512 + lane * 8);
        }

        // ---- O^T += V^T P^T (V frags shared across q-groups) ----
#pragma unroll
        for (int g2 = 0; g2 < 4; ++g2) {
            const short8 v0 = *(const short8*)(VS[buf] + (g2 * 2 + 0) * 512 + lane * 8);
            const short8 v1 = *(const short8*)(VS[buf] + (g2 * 2 + 1) * 512 + lane * 8);
#pragma unroll
            for (int u = 0; u < 2; ++u) {
                o_acc[g2][u] = MFMA16(v0, pf[u][0], o_acc[g2][u]);
                o_acc[g2][u] = MFMA16(v1, pf[u][1], o_acc[g2][u]);
            }
        }
        __syncthreads();
    }

    // ---- deferred l reduction + epilogue ----
    const int bb2 = bh >> 4, h2 = bh & 15;
#pragma unroll
    for (int u = 0; u < 2; ++u) {
        l_r[u] += __shfl_xor(l_r[u], 16);
        l_r[u] += __shfl_xor(l_r[u], 32);
        const float inv = 1.0f / l_r[u];
        const size_t m = (size_t)bb2 * T_ + qw + u * 16 + l16;
#pragma unroll
        for (int g2 = 0; g2 < 4; ++g2) {
            uint2 pk;
            pk.x = packrnu(o_acc[g2][u][0] * inv, o_acc[g2][u][1] * inv);
            pk.y = packrnu(o_acc[g2][u][2] * inv, o_acc[g2][u][3] * inv);
            *(uint2*)(AOc + m * KA + h2 * 64 + g2 * 16 + quad * 4) = pk;
        }
    }
}

// ---------------------------------------------------------------------------
extern "C" void kernel_launch(void* const* d_in, const int* in_sizes, int n_in,
                              void* d_out, int out_size, void* d_ws, size_t ws_size,
                              hipStream_t stream)
{
    const float* x       = (const float*)d_in[0];
    const float* qkv_w   = (const float*)d_in[1];
    const float* qkv_b   = (const float*)d_in[2];
    const float* out_w   = (const float*)d_in[3];
    const float* out_b   = (const float*)d_in[4];
    const float* rel_pos = (const float*)d_in[5];
    const float* rpe_w   = (const float*)d_in[6];
    float* out = (float*)d_out;

    const size_t QE = (size_t)B_ * H_ * T_ * HD_;  // 4,194,304
    ushort_t* Qs  = (ushort_t*)d_ws;
    ushort_t* Khi = Qs  + QE;
    ushort_t* Vt  = Khi + QE;
    ushort_t* Xc  = Vt  + QE;                  // [4096][1024]
    ushort_t* QWc = Xc  + (size_t)M_ * KA;     // [3072][1024]
    ushort_t* OWc = QWc + (size_t)N3D_ * KA;   // [1024][1024]
    ushort_t* AOc = OWc + (size_t)D_ * KA;     // [4096][1024]
    float* biasp  = (float*)(AOc + (size_t)M_ * KA);

    cvt_all<<<M_ + N3D_ + D_ + 1024, 256, 0, stream>>>(
        x, qkv_w, out_w, rel_pos, rpe_w, Xc, QWc, OWc, biasp);

    qkv_mfma<<<dim3(N3D_ / 128, M_ / 128), 256, 0, stream>>>(
        Xc, QWc, qkv_b, Qs, Khi, Vt);
    attn_mfma<<<512, 256, 0, stream>>>(Qs, Khi, Vt, biasp, AOc);
    out_mfma<<<dim3(D_ / 64, M_ / 128), 256, 0, stream>>>(
        AOc, OWc, out_b, out);
}

// Round 11
// 258.489 us; speedup vs baseline: 1.4591x; 1.0543x over previous
//
#include <hip/hip_runtime.h>
#include <math.h>

#define B_ 2
#define T_ 2048
#define D_ 1024
#define H_ 16
#define HD_ 64
#define MAXLEN_ 2048
#define N3D_ 3072
#define M_ (B_ * T_)   // 4096
#define KA 1024        // GEMM K (plain bf16)

#define SCALE_L2E 0.18033688011116215f   // 0.125 * log2(e)
#define L2E 1.4426950408889634f

typedef unsigned short ushort_t;
typedef __attribute__((ext_vector_type(8))) short short8;
typedef __attribute__((ext_vector_type(4))) float floatx4;
#define MFMA16(a, b, c) __builtin_amdgcn_mfma_f32_16x16x32_bf16(a, b, c, 0, 0, 0)

static __device__ __forceinline__ ushort_t f2bf(float f) {
    unsigned u = __float_as_uint(f);
    unsigned r = (u + 0x7FFFu + ((u >> 16) & 1u)) >> 16;
    return (ushort_t)r;
}
// round-half-up bf16 pair pack: add 0x8000 then take hi16 of each via v_perm.
static __device__ __forceinline__ unsigned packrnu(float a, float b) {
    unsigned ua = __float_as_uint(a) + 0x8000u;
    unsigned ub = __float_as_uint(b) + 0x8000u;
    return __builtin_amdgcn_perm(ub, ua, 0x07060302u);
}

// async global->LDS, 16B per lane; lds dst = wave-uniform base + lane*16
static __device__ __forceinline__ void gld16(const ushort_t* g, ushort_t* l) {
    __builtin_amdgcn_global_load_lds(
        (const __attribute__((address_space(1))) void*)g,
        (__attribute__((address_space(3))) void*)l, 16, 0, 0);
}

// ---------------------------------------------------------------------------
// Fused precompute: rows [0, 8192) convert x|qkv_w|out_w fp32->bf16;
// rows [8192, 9216) project rel_pos @ rpe_w (4 rows/block, 1 per wave).
// ---------------------------------------------------------------------------
__global__ __launch_bounds__(256) void cvt_all(
    const float* __restrict__ x, const float* __restrict__ qw,
    const float* __restrict__ ow, const float* __restrict__ rel_pos,
    const float* __restrict__ rpe_w,
    ushort_t* __restrict__ Xc, ushort_t* __restrict__ QWc,
    ushort_t* __restrict__ OWc, float* __restrict__ biasp)
{
    const int row = blockIdx.x;
    if (row < M_ + N3D_ + D_) {
        const float* src; ushort_t* dst; int r;
        if (row < M_)            { src = x;  dst = Xc;  r = row; }
        else if (row < M_ + N3D_){ src = qw; dst = QWc; r = row - M_; }
        else                     { src = ow; dst = OWc; r = row - M_ - N3D_; }
        const int c = threadIdx.x * 4;
        float4 v = *(const float4*)(src + (size_t)r * 1024 + c);
        ushort4 hv;
        hv.x = f2bf(v.x); hv.y = f2bf(v.y); hv.z = f2bf(v.z); hv.w = f2bf(v.w);
        *(ushort4*)(dst + (size_t)r * KA + c) = hv;
    } else {
        const int wv = threadIdx.x >> 6, lane = threadIdx.x & 63;
        const int r = (row - (M_ + N3D_ + D_)) * 4 + wv;
        if (r < 2 * MAXLEN_ - 1) {
            float v = rel_pos[(size_t)r * HD_ + lane] * rpe_w[lane];
#pragma unroll
            for (int off = 32; off; off >>= 1) v += __shfl_down(v, off);
            if (lane == 0) biasp[r] = v * L2E;
        }
    }
}

// ---------------------------------------------------------------------------
// qkv MFMA GEMM. M=4096, N=3072, K=1024 bf16. 128x128 tile, 4 waves.
// Epilogue: Q -> Qs (pre-scaled by 0.125*log2e), K -> Khi, V -> Vt [B,H,HD,T].
// ---------------------------------------------------------------------------
__global__ __launch_bounds__(256) void qkv_mfma(
    const ushort_t* __restrict__ Ac, const ushort_t* __restrict__ Bc,
    const float* __restrict__ bias,
    ushort_t* __restrict__ Qs, ushort_t* __restrict__ Khi,
    ushort_t* __restrict__ Vt)
{
    __shared__ __align__(16) ushort_t As[16 * 512];
    __shared__ __align__(16) ushort_t Bs[16 * 512];
    const int tid = threadIdx.x;
    const int wv = tid >> 6, lane = tid & 63;
    const int l16 = lane & 15, quad = lane >> 4;
    const int wm = wv & 1, wn = wv >> 1;
    const int m0 = blockIdx.y * 128, n0 = blockIdx.x * 128;

    floatx4 acc[4][4];
#pragma unroll
    for (int i = 0; i < 4; ++i)
#pragma unroll
        for (int j = 0; j < 4; ++j) acc[i][j] = (floatx4){0.f, 0.f, 0.f, 0.f};

    for (int k0 = 0; k0 < KA; k0 += 64) {
        __syncthreads();
#pragma unroll
        for (int c = 0; c < 4; ++c) {
            const int b = wv * 4 + c;
            const int i = b >> 1, ks = b & 1;
            const int k = k0 + ks * 32 + quad * 8;
            gld16(Ac + (size_t)(m0 + i * 16 + l16) * KA + k, As + b * 512);
            gld16(Bc + (size_t)(n0 + i * 16 + l16) * KA + k, Bs + b * 512);
        }
        __syncthreads();
#pragma unroll
        for (int ks = 0; ks < 2; ++ks) {
            short8 af[4], bf[4];
#pragma unroll
            for (int ii = 0; ii < 4; ++ii)
                af[ii] = *(const short8*)(As + ((wm * 4 + ii) * 2 + ks) * 512 + lane * 8);
#pragma unroll
            for (int jj = 0; jj < 4; ++jj)
                bf[jj] = *(const short8*)(Bs + ((wn * 4 + jj) * 2 + ks) * 512 + lane * 8);
#pragma unroll
            for (int ii = 0; ii < 4; ++ii)
#pragma unroll
                for (int jj = 0; jj < 4; ++jj)
                    acc[ii][jj] = MFMA16(af[ii], bf[jj], acc[ii][jj]);
        }
    }

#pragma unroll
    for (int ii = 0; ii < 4; ++ii) {
#pragma unroll
        for (int r = 0; r < 4; ++r) {
            const int m = m0 + wm * 64 + ii * 16 + quad * 4 + r;
            const int bb = m >> 11, t = m & 2047;
#pragma unroll
            for (int jj = 0; jj < 4; ++jj) {
                const int n = n0 + wn * 64 + jj * 16 + l16;
                const int c = n >> 10, h = (n >> 6) & 15, hd = n & 63;
                const float v = acc[ii][jj][r] + bias[n];
                const size_t idx = (((size_t)bb * H_ + h) * T_ + t) * HD_ + hd;
                if (c == 0) { Qs[idx] = f2bf(v * SCALE_L2E); }
                else if (c == 1) { Khi[idx] = f2bf(v); }
                else { Vt[(((size_t)bb * H_ + h) * HD_ + hd) * T_ + t] = f2bf(v); }
            }
        }
    }
}

// ---------------------------------------------------------------------------
// out MFMA GEMM. M=4096, N=1024, K=1024. 128x64 tile (grid 512 = 2/CU).
// ---------------------------------------------------------------------------
__global__ __launch_bounds__(256) void out_mfma(
    const ushort_t* __restrict__ Ac, const ushort_t* __restrict__ Bc,
    const float* __restrict__ bias, float* __restrict__ Out)
{
    __shared__ __align__(16) ushort_t As[16 * 512];
    __shared__ __align__(16) ushort_t Bs[8 * 512];
    const int tid = threadIdx.x;
    const int wv = tid >> 6, lane = tid & 63;
    const int l16 = lane & 15, quad = lane >> 4;
    const int wm = wv & 1, wn = wv >> 1;
    const int m0 = blockIdx.y * 128, n0 = blockIdx.x * 64;

    floatx4 acc[4][2];
#pragma unroll
    for (int i = 0; i < 4; ++i)
#pragma unroll
        for (int j = 0; j < 2; ++j) acc[i][j] = (floatx4){0.f, 0.f, 0.f, 0.f};

    for (int k0 = 0; k0 < KA; k0 += 64) {
        __syncthreads();
#pragma unroll
        for (int c = 0; c < 4; ++c) {
            const int b = wv * 4 + c;
            const int i = b >> 1, ks = b & 1;
            const int k = k0 + ks * 32 + quad * 8;
            gld16(Ac + (size_t)(m0 + i * 16 + l16) * KA + k, As + b * 512);
        }
#pragma unroll
        for (int c = 0; c < 2; ++c) {
            const int b = wv * 2 + c;
            const int j = b >> 1, ks = b & 1;
            const int k = k0 + ks * 32 + quad * 8;
            gld16(Bc + (size_t)(n0 + j * 16 + l16) * KA + k, Bs + b * 512);
        }
        __syncthreads();
#pragma unroll
        for (int ks = 0; ks < 2; ++ks) {
            short8 af[4], bf[2];
#pragma unroll
            for (int ii = 0; ii < 4; ++ii)
                af[ii] = *(const short8*)(As + ((wm * 4 + ii) * 2 + ks) * 512 + lane * 8);
#pragma unroll
            for (int jj = 0; jj < 2; ++jj)
                bf[jj] = *(const short8*)(Bs + ((wn * 2 + jj) * 2 + ks) * 512 + lane * 8);
#pragma unroll
            for (int ii = 0; ii < 4; ++ii)
#pragma unroll
                for (int jj = 0; jj < 2; ++jj)
                    acc[ii][jj] = MFMA16(af[ii], bf[jj], acc[ii][jj]);
        }
    }

#pragma unroll
    for (int ii = 0; ii < 4; ++ii) {
#pragma unroll
        for (int r = 0; r < 4; ++r) {
            const int m = m0 + wm * 64 + ii * 16 + quad * 4 + r;
#pragma unroll
            for (int jj = 0; jj < 2; ++jj) {
                const int n = n0 + wn * 32 + jj * 16 + l16;
                Out[(size_t)m * D_ + n] = acc[ii][jj][r] + bias[n];
            }
        }
    }
}

// ---------------------------------------------------------------------------
// Flash attention v5: v4 core + vmcnt-ordering fix.
// Bias float4s for tile t are loaded BEFORE the tile t+1 prefetch is issued,
// so consuming them waits only vmcnt(8) (prefetch may remain outstanding) --
// previously bias loads sat behind the prefetch in the in-order vmcnt queue,
// forcing a full prefetch drain every tile. Bias enters via MFMA C-operand.
// ---------------------------------------------------------------------------
__global__ __launch_bounds__(256) void attn_mfma(
    const ushort_t* __restrict__ Qs, const ushort_t* __restrict__ Khi,
    const ushort_t* __restrict__ Vt, const float* __restrict__ biasp,
    ushort_t* __restrict__ AOc)
{
    __shared__ __align__(16) ushort_t KS[2][8 * 512];   // 16 KB
    __shared__ __align__(16) ushort_t VS[2][8 * 512];   // 16 KB
    __shared__ __align__(16) ushort_t PS[4][2][1024];   // 16 KB: wave, qgroup

    // XCD swizzle: 16 q-tiles of one bh stay on one XCD slot
    const int i = blockIdx.x;
    const int j = i >> 3;
    const int bh = (i & 7) + 8 * (j >> 4);
    const int q0 = (j & 15) * 128;
    const int tid = threadIdx.x;
    const int wv = tid >> 6, lane = tid & 63;
    const int l16 = lane & 15, quad = lane >> 4;

    const int qw = q0 + wv * 32;

    // Q B-fragments for the wave's two 16-col groups (persistent)
    short8 qh[2][2];
#pragma unroll
    for (int u = 0; u < 2; ++u) {
        const size_t qoff = ((size_t)bh * T_ + qw + u * 16 + l16) * HD_ + quad * 8;
        qh[u][0] = *(const short8*)(Qs + qoff);
        qh[u][1] = *(const short8*)(Qs + qoff + 32);
    }

    float l_r[2] = {0.f, 0.f};
    floatx4 o_acc[4][2];
#pragma unroll
    for (int g2 = 0; g2 < 4; ++g2)
#pragma unroll
        for (int u = 0; u < 2; ++u) o_acc[g2][u] = (floatx4){0.f, 0.f, 0.f, 0.f};

    const ushort_t* gK = Khi + (size_t)bh * T_ * HD_;
    const ushort_t* gV = Vt + (size_t)bh * HD_ * T_;
    // bias window base for u=1 (u=0 base = this + 16); >= 0 for all lanes
    const int c0base = 2047 + quad * 4 - (qw + 16 + l16);
    const int qdbase = quad >> 1;

    const size_t kstage = (size_t)(wv * 16 + l16) * HD_ + quad * 8;
    const size_t vstage = (size_t)(wv * 16 + l16) * T_ + quad * 8;

    // prologue: stage tile 0 into buffer 0
    gld16(gK + kstage,      KS[0] + (wv * 2 + 0) * 512);
    gld16(gK + kstage + 32, KS[0] + (wv * 2 + 1) * 512);
    gld16(gV + vstage,      VS[0] + (wv * 2 + 0) * 512);
    gld16(gV + vstage + 32, VS[0] + (wv * 2 + 1) * 512);
    __syncthreads();

    for (int t = 0; t < 32; ++t) {
        const int k0 = t * 64;
        const int buf = t & 1, nbuf = buf ^ 1;

        // ---- bias loads FIRST (before prefetch -> clean vmcnt ordering) ----
        // f4[z] = biasp[c0base + k0 + z*16 .. +3]; u=0,g uses f4[g+1]; u=1,g uses f4[g]
        float4 f4[5];
        {
            const float* bp = biasp + (c0base + k0);
#pragma unroll
            for (int z = 0; z < 5; ++z)
                __builtin_memcpy(&f4[z], bp + z * 16, 16);
        }

        // ---- prefetch tile t+1 into the other buffer ----
        if (t < 31) {
            const size_t koff = kstage + (size_t)(k0 + 64) * HD_;
            gld16(gK + koff,      KS[nbuf] + (wv * 2 + 0) * 512);
            gld16(gK + koff + 32, KS[nbuf] + (wv * 2 + 1) * 512);
            const size_t voff = vstage + (size_t)(k0 + 64);
            gld16(gV + voff,      VS[nbuf] + (wv * 2 + 0) * 512);
            gld16(gV + voff + 32, VS[nbuf] + (wv * 2 + 1) * 512);
        }

        // ---- S^T = K x Q + bias (via C-operand); p = exp2(s) ----
#pragma unroll
        for (int g = 0; g < 4; ++g) {
            const short8 kh0 = *(const short8*)(KS[buf] + (g * 2 + 0) * 512 + lane * 8);
            const short8 kh1 = *(const short8*)(KS[buf] + (g * 2 + 1) * 512 + lane * 8);
            const int qd = 2 * (g & 1) + qdbase;
#pragma unroll
            for (int u = 0; u < 2; ++u) {
                const float4 bbv = f4[g + 1 - u];
                floatx4 a = (floatx4){bbv.x, bbv.y, bbv.z, bbv.w};
                a = MFMA16(kh0, qh[u][0], a);
                a = MFMA16(kh1, qh[u][1], a);
                const float p0 = __builtin_amdgcn_exp2f(a[0]);
                const float p1 = __builtin_amdgcn_exp2f(a[1]);
                const float p2 = __builtin_amdgcn_exp2f(a[2]);
                const float p3 = __builtin_amdgcn_exp2f(a[3]);
                l_r[u] += (p0 + p1) + (p2 + p3);
                uint2 pkd;
                pkd.x = packrnu(p0, p1);
                pkd.y = packrnu(p2, p3);
                *(uint2*)(PS[wv][u] + (g >> 1) * 512 + (qd * 16 + l16) * 8 + (quad & 1) * 4) = pkd;
            }
        }

        // ---- P frag reads (wave-internal dependency) ----
        short8 pf[2][2];
#pragma unroll
        for (int u = 0; u < 2; ++u) {
            pf[u][0] = *(const short8*)(PS[wv][u] + lane * 8);
            pf[u][1] = *(const short8*)(PS[wv][u] + 512 + lane * 8);
        }

        // ---- O^T += V^T P^T (V frags shared across q-groups) ----
#pragma unroll
        for (int g2 = 0; g2 < 4; ++g2) {
            const short8 v0 = *(const short8*)(VS[buf] + (g2 * 2 + 0) * 512 + lane * 8);
            const short8 v1 = *(const short8*)(VS[buf] + (g2 * 2 + 1) * 512 + lane * 8);
#pragma unroll
            for (int u = 0; u < 2; ++u) {
                o_acc[g2][u] = MFMA16(v0, pf[u][0], o_acc[g2][u]);
                o_acc[g2][u] = MFMA16(v1, pf[u][1], o_acc[g2][u]);
            }
        }
        __syncthreads();
    }

    // ---- deferred l reduction + epilogue ----
    const int bb2 = bh >> 4, h2 = bh & 15;
#pragma unroll
    for (int u = 0; u < 2; ++u) {
        l_r[u] += __shfl_xor(l_r[u], 16);
        l_r[u] += __shfl_xor(l_r[u], 32);
        const float inv = 1.0f / l_r[u];
        const size_t m = (size_t)bb2 * T_ + qw + u * 16 + l16;
#pragma unroll
        for (int g2 = 0; g2 < 4; ++g2) {
            uint2 pk;
            pk.x = packrnu(o_acc[g2][u][0] * inv, o_acc[g2][u][1] * inv);
            pk.y = packrnu(o_acc[g2][u][2] * inv, o_acc[g2][u][3] * inv);
            *(uint2*)(AOc + m * KA + h2 * 64 + g2 * 16 + quad * 4) = pk;
        }
    }
}

// ---------------------------------------------------------------------------
extern "C" void kernel_launch(void* const* d_in, const int* in_sizes, int n_in,
                              void* d_out, int out_size, void* d_ws, size_t ws_size,
                              hipStream_t stream)
{
    const float* x       = (const float*)d_in[0];
    const float* qkv_w   = (const float*)d_in[1];
    const float* qkv_b   = (const float*)d_in[2];
    const float* out_w   = (const float*)d_in[3];
    const float* out_b   = (const float*)d_in[4];
    const float* rel_pos = (const float*)d_in[5];
    const float* rpe_w   = (const float*)d_in[6];
    float* out = (float*)d_out;

    const size_t QE = (size_t)B_ * H_ * T_ * HD_;  // 4,194,304
    ushort_t* Qs  = (ushort_t*)d_ws;
    ushort_t* Khi = Qs  + QE;
    ushort_t* Vt  = Khi + QE;
    ushort_t* Xc  = Vt  + QE;                  // [4096][1024]
    ushort_t* QWc = Xc  + (size_t)M_ * KA;     // [3072][1024]
    ushort_t* OWc = QWc + (size_t)N3D_ * KA;   // [1024][1024]
    ushort_t* AOc = OWc + (size_t)D_ * KA;     // [4096][1024]
    float* biasp  = (float*)(AOc + (size_t)M_ * KA);

    cvt_all<<<M_ + N3D_ + D_ + 1024, 256, 0, stream>>>(
        x, qkv_w, out_w, rel_pos, rpe_w, Xc, QWc, OWc, biasp);

    qkv_mfma<<<dim3(N3D_ / 128, M_ / 128), 256, 0, stream>>>(
        Xc, QWc, qkv_b, Qs, Khi, Vt);
    attn_mfma<<<512, 256, 0, stream>>>(Qs, Khi, Vt, biasp, AOc);
    out_mfma<<<dim3(D_ / 64, M_ / 128), 256, 0, stream>>>(
        AOc, OWc, out_b, out);
}